// Round 13
// baseline (15.249 us; speedup 1.0000x reference)
//
#include <hip/hip_runtime.h>
#include <math.h>
#include <type_traits>

#define NQ     12
#define DIM    4096
#define DEPTH  6
#define NBATCH 256
#define NT     512     // 8 waves per block -> 2 waves per SIMD
#define NREG   8       // state elements per thread

// ---------------------------------------------------------------------------
// CNOT-ladder perm = Gray map g(j)=j^(j>>1), linear over GF(2)^12; all perms
// folded into gates: depth-d gate on logical bit b = butterfly on XOR-axis
// V = A^d e_b, sign selector M = row b of A^{-d} (A^16=I):
//   new[j] = x[j] + tau(j)*x[j^V],  tau(j) = parity(M&j) ? +t : -t, t=tan(th/2)
// (tan-normalized; global scale prod(cos) applied once in the observer).
// Storage j = (tid<<3)|r, tid 0..511, r 0..7.
//
// ROUND 13 = R9 champion (14.38us) + two chain-cuts, no new primitives:
//  (1) DPP-class lane gates fused in pairs (b3,b4) and (b5,b6):
//      x'' = x + spA*P_A + spB*P_B + spAB*P_AB, composite axis VA^VB still
//      DPP-class; sigma = parity(MA&VB) constexpr. 6 serial lane stages -> 4.
//      (Pairs never include DS-class gates b=7,8: composite would add DS ops.)
//  (2) gate9x's LDS write embedded in cross2's compute loop (post-cross2
//      value stored to lds9 immediately; separate write block removed).
// Permlane retired (R10/R11 net-negative); pad dropped (R12 neutral).
// ---------------------------------------------------------------------------

__host__ __device__ constexpr unsigned axmask(int d, int b) {
    unsigned m = 1u << b;
    for (int i = 0; i < d; ++i) m = (m ^ (m >> 1)) & 0xFFFu;
    return m;
}
__host__ __device__ constexpr unsigned selmask(int d, int b) {
    unsigned m = 1u << b;
    for (int i = 0; i < 16 - d; ++i) m = (m ^ ((m << 1) & 0xFFFu)) & 0xFFFu;
    return m;
}
__host__ __device__ constexpr int cpopc(unsigned v) {
    int c = 0; while (v) { c += (int)(v & 1u); v >>= 1; } return c;
}

template<int I, int N, class F>
__device__ __forceinline__ void sfor(F&& f) {
    if constexpr (I < N) {
        f(std::integral_constant<int, I>{});
        sfor<I + 1, N>(static_cast<F&&>(f));
    }
}

// ---- cross-lane primitives (R5/R7/R9-proven set ONLY) ----
template<int CTRL>
__device__ __forceinline__ float dppx(float v) {
    int iv = __float_as_int(v);
    return __int_as_float(__builtin_amdgcn_update_dpp(iv, iv, CTRL, 0xF, 0xF, false));
}
template<int M4>
__device__ __forceinline__ float lxor_low(float v) {
    static_assert(M4 >= 1 && M4 <= 15, "low mask");
    if constexpr      (M4 == 1)  return dppx<0xB1>(v);    // quad_perm xor1
    else if constexpr (M4 == 2)  return dppx<0x4E>(v);    // quad_perm xor2
    else if constexpr (M4 == 3)  return dppx<0x1B>(v);    // quad_perm xor3
    else if constexpr (M4 == 7)  return dppx<0x141>(v);   // row_half_mirror
    else if constexpr (M4 == 15) return dppx<0x140>(v);   // row_mirror
    else if constexpr ((M4 & 8) == 0)   // 4,5,6 = 7 ^ {3,2,1}
        return lxor_low<M4 ^ 7>(dppx<0x141>(v));
    else                                // 8..14 = 15 ^ {7..1}
        return lxor_low<M4 ^ 15>(dppx<0x140>(v));
}
template<int MASK>
__device__ __forceinline__ float lxor(float v) {
    static_assert(MASK > 0 && MASK < 64, "lane mask");
    if constexpr (MASK >= 32) {
        return __shfl_xor(v, MASK, 64);
    } else if constexpr (MASK >= 16) {
        // ds_swizzle BitMode: (xor<<10) | (or<<5) | and(0x1F)
        return __int_as_float(__builtin_amdgcn_ds_swizzle(__float_as_int(v),
                                                          (MASK << 10) | 0x1F));
    } else {
        return lxor_low<MASK>(v);
    }
}

// swizzled LDS word address: thread t, chunk k in 0..1, 8 floats/thread
__device__ __forceinline__ int lad(int t, int k) {
    return t * 8 + 4 * (k ^ ((t >> 2) & 1));
}

// ---- pure-register gate (b<=2), tan form: 1 fma/elem ----
template<int D, int B>
__device__ __forceinline__ void gate_reg(float (&st)[NREG], int tid, float t) {
    constexpr unsigned V = axmask(D, B), M = selmask(D, B);
    static_assert((V >> 3) == 0 && V != 0, "reg gate");
    constexpr int VR = (int)V;
    constexpr unsigned MR = M & 7u, MT = M >> 3;
    const float tp = (__popc(MT & (unsigned)tid) & 1) ? t : -t;
    const float tn = -tp;
    sfor<0, NREG>([&](auto RC) {
        constexpr int r = RC.value, r2 = r ^ VR;
        if constexpr (r2 > r) {
            constexpr bool p0 = (cpopc(MR & (unsigned)r)  & 1) != 0;
            constexpr bool p1 = (cpopc(MR & (unsigned)r2) & 1) != 0;
            float a0 = st[r];
            st[r]  = fmaf(p0 ? tn : tp, st[r2], st[r]);
            st[r2] = fmaf(p1 ? tn : tp, a0,     st[r2]);
        }
    });
}

// ---- single intra-wave lane-crossing gate (b=7,8: DS-class), tan form ----
template<int D, int B>
__device__ __forceinline__ void gate_lane(float (&st)[NREG], int tid, float t) {
    constexpr unsigned V = axmask(D, B), M = selmask(D, B);
    constexpr int VT = (int)(V >> 3), VR = (int)(V & 7u);
    static_assert(VT > 0 && VT < 64, "intra-wave gate");
    static_assert((M & 7u) == 0, "no reg bits in selector for b>=3");
    const float tp = (__popc((M >> 3) & (unsigned)tid) & 1) ? t : -t;
    if constexpr (VR == 0) {
        sfor<0, NREG>([&](auto RC) {
            constexpr int r = RC.value;
            float p = lxor<VT>(st[r]);      // SIMD-lockstep: reads pre-update
            st[r] = fmaf(tp, p, st[r]);
        });
    } else {
        sfor<0, NREG>([&](auto RC) {
            constexpr int r = RC.value, r2 = r ^ VR;
            if constexpr (r2 > r) {
                float pa = lxor<VT>(st[r2]);
                float pb = lxor<VT>(st[r]);
                st[r]  = fmaf(tp, pa, st[r]);
                st[r2] = fmaf(tp, pb, st[r2]);
            }
        });
    }
}

// ---- fused pair of intra-wave gates (both DPP-class), applied A then B ----
template<int D, int BA, int BB>
__device__ __forceinline__ void gate_pair(float (&st)[NREG], int tid,
                                          float tA, float tB) {
    constexpr unsigned VA = axmask(D, BA), MA = selmask(D, BA);
    constexpr unsigned VB = axmask(D, BB), MB = selmask(D, BB);
    constexpr int VTA = (int)(VA >> 3), VRA = (int)(VA & 7u);
    constexpr int VTB = (int)(VB >> 3), VRB = (int)(VB & 7u);
    constexpr int VTC = VTA ^ VTB,      VRC = VRA ^ VRB;
    static_assert(VTA > 0 && VTA < 16 && VTB > 0 && VTB < 16, "DPP-class only");
    static_assert(VTC > 0 && VTC < 16, "composite stays DPP-class");
    static_assert(((MA | MB) & 7u) == 0, "no reg bits in selectors");
    // x'' = x + tauA x^VA + tauB x^VB + sigma tauA tauB x^(VA^VB),
    // sigma = (-1)^parity(MA & VB)   (apply A first, then B)
    constexpr bool sgn = (cpopc(MA & VB) & 1) != 0;
    const float spA = (__popc((MA >> 3) & (unsigned)tid) & 1) ? tA : -tA;
    const float spB = (__popc((MB >> 3) & (unsigned)tid) & 1) ? tB : -tB;
    const float spC = (sgn ? -1.f : 1.f) * spA * spB;

    float nv[NREG];
    sfor<0, NREG>([&](auto RC) {
        constexpr int r = RC.value;
        float pa = lxor<VTA>(st[r ^ VRA]);
        float pb = lxor<VTB>(st[r ^ VRB]);
        float pc = lxor<VTC>(st[r ^ VRC]);
        float t  = fmaf(spA, pa, st[r]);
        t        = fmaf(spB, pb, t);
        nv[r]    = fmaf(spC, pc, t);
    });
    sfor<0, NREG>([&](auto RC) { st[RC.value] = nv[RC.value]; });
}

// ---- fused cross pair (b=11,10) with embedded gate9x write; then b=9 ----
template<int D>
__device__ __forceinline__ void cross_block(float (&st)[NREG], int tid,
                                            float t1, float t2, float t9,
                                            float* __restrict__ lds2,
                                            float* __restrict__ lds9) {
    constexpr unsigned V1 = axmask(D, 11), V2 = axmask(D, 10), V9 = axmask(D, 9);
    constexpr unsigned M1 = selmask(D, 11), M2 = selmask(D, 10), M9 = selmask(D, 9);
    static_assert(((V1 | V2 | V9) & 7u) == 0, "cross axes reg-free");
    static_assert(((M1 | M2 | M9) & 7u) == 0, "cross masks reg-free");
    constexpr int T1 = (int)(V1 >> 3), T2 = (int)(V2 >> 3), T9 = (int)(V9 >> 3);
    static_assert((cpopc(M1 & V2) & 1) == 0, "kC sign identity");
    static_assert(T9 >= 64 && T9 < 512, "b9 crosses waves");

    const float t1p = (__popc((M1 >> 3) & (unsigned)tid) & 1) ? t1 : -t1;
    const float t2p = (__popc((M2 >> 3) & (unsigned)tid) & 1) ? t2 : -t2;
    const float t12 = t1p * t2p;
    const float t9p = (__popc((M9 >> 3) & (unsigned)tid) & 1) ? t9 : -t9;

    float* buf2 = lds2 + (D & 1) * DIM;
    float* buf9 = lds9 + (D & 1) * DIM;

    // write pre-cross2 state
    sfor<0, 2>([&](auto KC) {
        constexpr int k = KC.value;
        *reinterpret_cast<float4*>(&buf2[lad(tid, k)]) =
            make_float4(st[4*k], st[4*k+1], st[4*k+2], st[4*k+3]);
    });
    __syncthreads();
    // read 3 partners, apply cross2, immediately stage result for gate9x
    const int p1 = tid ^ T1, p2 = tid ^ T2, p3 = tid ^ (T1 ^ T2);
    sfor<0, 2>([&](auto KC) {
        constexpr int k = KC.value;
        float4 A  = *reinterpret_cast<const float4*>(&buf2[lad(p1, k)]);
        float4 Bv = *reinterpret_cast<const float4*>(&buf2[lad(p2, k)]);
        float4 Cv = *reinterpret_cast<const float4*>(&buf2[lad(p3, k)]);
        float t;
        t = fmaf(t1p, A.x, st[4*k+0]); t = fmaf(t2p, Bv.x, t); st[4*k+0] = fmaf(t12, Cv.x, t);
        t = fmaf(t1p, A.y, st[4*k+1]); t = fmaf(t2p, Bv.y, t); st[4*k+1] = fmaf(t12, Cv.y, t);
        t = fmaf(t1p, A.z, st[4*k+2]); t = fmaf(t2p, Bv.z, t); st[4*k+2] = fmaf(t12, Cv.z, t);
        t = fmaf(t1p, A.w, st[4*k+3]); t = fmaf(t2p, Bv.w, t); st[4*k+3] = fmaf(t12, Cv.w, t);
        *reinterpret_cast<float4*>(&buf9[lad(tid, k)]) =
            make_float4(st[4*k], st[4*k+1], st[4*k+2], st[4*k+3]);
    });
    __syncthreads();
    // gate9x read + apply
    const int p9 = tid ^ T9;
    sfor<0, 2>([&](auto KC) {
        constexpr int k = KC.value;
        float4 pv = *reinterpret_cast<const float4*>(&buf9[lad(p9, k)]);
        st[4*k+0] = fmaf(t9p, pv.x, st[4*k+0]);
        st[4*k+1] = fmaf(t9p, pv.y, st[4*k+1]);
        st[4*k+2] = fmaf(t9p, pv.z, st[4*k+2]);
        st[4*k+3] = fmaf(t9p, pv.w, st[4*k+3]);
    });
}

// ---- one depth ----
template<int D>
__device__ __forceinline__ void depth_apply(float (&st)[NREG], int tid,
                                            const float* __restrict__ tsh,
                                            float* __restrict__ lds2,
                                            float* __restrict__ lds9) {
    float4 ta = *reinterpret_cast<const float4*>(&tsh[D * 12 + 0]);
    float4 tb = *reinterpret_cast<const float4*>(&tsh[D * 12 + 4]);
    float4 tc = *reinterpret_cast<const float4*>(&tsh[D * 12 + 8]);
    float tq[12] = {ta.x, ta.y, ta.z, ta.w, tb.x, tb.y, tb.z, tb.w,
                    tc.x, tc.y, tc.z, tc.w};
    // b = 11, 10 (fused cross2) + b = 9, with embedded staging
    cross_block<D>(st, tid, tq[0], tq[1], tq[2], lds2, lds9);
    // b = 8, 7: DS-class single gates (tq[3], tq[4])
    gate_lane<D, 8>(st, tid, tq[3]);
    gate_lane<D, 7>(st, tid, tq[4]);
    // b = 6,5 and 4,3: DPP-class fused pairs (apply b6 then b5; b4 then b3)
    gate_pair<D, 6, 5>(st, tid, tq[5], tq[6]);
    gate_pair<D, 4, 3>(st, tid, tq[7], tq[8]);
    // b = 2, 1, 0: register butterflies
    gate_reg<D, 2>(st, tid, tq[9]);
    gate_reg<D, 1>(st, tid, tq[10]);
    gate_reg<D, 0>(st, tid, tq[11]);
}

__global__ __launch_bounds__(NT, 2)
void qnet_kernel(const float* __restrict__ x,       // [NBATCH, NQ]
                 const float* __restrict__ thetas,  // [DEPTH, NQ]
                 float* __restrict__ out)           // [NBATCH, 3]
{
    __shared__ __align__(16) float lds2[2 * DIM];   // 32 KB cross2 buffers
    __shared__ __align__(16) float lds9[2 * DIM];   // 32 KB gate9 buffers
    __shared__ __align__(16) float tsh[80];         // tan table (72 used)
    __shared__ __align__(16) float csh[80];         // cos table (72 used)
    __shared__ float red[8];                        // per-wave sums

    const int b   = blockIdx.x;
    const int tid = threadIdx.x;

    // ---- gate trig tables, once per block ----
    if (tid < 72) {
        float rev = thetas[tid] * 0.07957747154594767f;  // (th/2)/(2pi)
        float cc  = __builtin_amdgcn_cosf(rev);
        float ss  = __builtin_amdgcn_sinf(rev);
        csh[tid] = cc;
        tsh[tid] = ss * __builtin_amdgcn_rcpf(cc);
    }

    // ---- encoder: x*pi/2 rad = x/4 rev ----
    const float4* xv = reinterpret_cast<const float4*>(x + b * 12);
    float4 xa = xv[0], xb = xv[1], xc = xv[2];
    float xs[12] = {xa.x, xa.y, xa.z, xa.w, xb.x, xb.y, xb.z, xb.w,
                    xc.x, xc.y, xc.z, xc.w};
    float cq[12], sq[12];
    sfor<0, 12>([&](auto QC) {
        constexpr int q = QC.value;
        float rev = xs[q] * 0.25f;
        sq[q] = __builtin_amdgcn_sinf(rev);
        cq[q] = __builtin_amdgcn_cosf(rev);
    });

    // product state: j = (tid<<3)|r; j bit (3+i) = tid bit i <-> qubit 8-i;
    // j bit i (i<3) = reg bit i <-> qubit 11-i
    float la = 1.0f;
    sfor<0, 9>([&](auto IC) {
        constexpr int i = IC.value;
        la *= ((tid >> i) & 1) ? sq[8 - i] : cq[8 - i];
    });
    float st[NREG];
    st[0] = la;
    sfor<0, 3>([&](auto IC) {
        constexpr int i = IC.value;
        sfor<0, (1 << i)>([&](auto KC) {
            constexpr int k = KC.value;
            float base = st[k];
            st[k + (1 << i)] = base * sq[11 - i];
            st[k]            = base * cq[11 - i];
        });
    });

    __syncthreads();   // trig tables ready

    // ---- 6 depths ----
    sfor<0, 6>([&](auto DC) {
        depth_apply<DC.value>(st, tid, tsh, lds2, lds9);
    });

    // ---- global scale: sc = prod of all 72 cos ----
    float sc = 1.0f;
    sfor<0, 18>([&](auto IC) {
        constexpr int i = IC.value;
        float4 c4 = *reinterpret_cast<const float4*>(&csh[4 * i]);
        sc *= (c4.x * c4.y) * (c4.z * c4.w);
    });

    // ---- observer ----
    float tot = 0.0f;
    sfor<0, NREG>([&](auto RC) {
        constexpr int r = RC.value;
        tot = fmaf(st[r], st[r], tot);
    });
    tot *= sc * sc;   // undo tan normalization once

    // full 64-lane butterfly sum
    float v = tot;
    v += lxor<1>(v);
    v += lxor<2>(v);
    v += lxor<4>(v);
    v += lxor<8>(v);
    v += lxor<16>(v);
    v += lxor<32>(v);
    const int w = tid >> 6;
    if ((tid & 63) == 0) red[w] = v;
    __syncthreads();
    // signs on stored index: q0 -> j bit 11 = w bit 2; q1 -> j bit 10 = w bit 1;
    // q2 -> j bits 11^9 = w bits 2^0
    if (tid < 3) {
        float acc = 0.0f;
        #pragma unroll
        for (int ww = 0; ww < 8; ++ww) {
            int par = (tid == 0) ? ((ww >> 2) & 1)
                    : (tid == 1) ? ((ww >> 1) & 1)
                    :              (((ww >> 2) ^ ww) & 1);
            acc += par ? -red[ww] : red[ww];
        }
        out[b * 3 + tid] = acc;
    }
}

extern "C" void kernel_launch(void* const* d_in, const int* in_sizes, int n_in,
                              void* d_out, int out_size, void* d_ws, size_t ws_size,
                              hipStream_t stream) {
    (void)in_sizes; (void)n_in; (void)out_size; (void)d_ws; (void)ws_size;
    const float* x      = (const float*)d_in[0];   // [256,12] f32
    const float* thetas = (const float*)d_in[1];   // [6,12]   f32
    float* out          = (float*)d_out;           // [256,3]  f32

    qnet_kernel<<<dim3(NBATCH), dim3(NT), 0, stream>>>(x, thetas, out);
}

// Round 14
// 14.964 us; speedup vs baseline: 1.0190x; 1.0190x over previous
//
#include <hip/hip_runtime.h>
#include <math.h>
#include <type_traits>

#define NQ     12
#define DIM    4096
#define DEPTH  6
#define NBATCH 256
#define NT     1024    // 16 waves per block -> 4 waves per SIMD (max for 1 block)
#define NREG   4       // state elements per thread

// ---------------------------------------------------------------------------
// CNOT-ladder perm = Gray map g(j)=j^(j>>1), linear over GF(2)^12; all perms
// folded into gates: depth-d gate on logical bit b = butterfly on XOR-axis
// V = A^d e_b, sign selector M = row b of A^{-d} (A^16=I):
//   new[j] = x[j] + tau(j)*x[j^V],  tau(j) = parity(M&j) ? +t : -t, t=tan(th/2)
// (tan-normalized; global scale prod(cos) applied once in the observer).
//
// ROUND 14: extend the ONLY repeatably-positive late-game lever (waves/SIMD,
// R7->R9 = -1.3us) to its max: NT=1024, NREG=4, 4 waves/SIMD.
// Layout j = (tid<<2)|r, tid 0..1023, r 0..3.
//   b<=1    -> register butterfly (reg bits 0,1)
//   b=2..7  -> intra-wave lane-xor (tid bits 0..5), proven classes:
//              DPP(<16) / ds_swizzle(16..31) / shfl_xor(>=32)
//   b=8..11 -> thread-crossing (tid bits 6..9 are wave bits): TWO fused
//              cross2 exchanges (b11,b10) and (b9,b8), general constexpr
//              sigma sign, 1xF4 write + 3xF4 reads, 1 barrier each.
// V&3==0 and M&3==0 for all b>=2 (axis spreads down max 5 bits; selector
// spreads up) -> static_asserted. Observer signs are wave-uniform
// (wave bits 3,2,3^1) -> single unsigned butterfly + 16-way LDS combine.
// R13's gate_pair fusion retired (added lxor work, regressed).
// ---------------------------------------------------------------------------

__host__ __device__ constexpr unsigned axmask(int d, int b) {
    unsigned m = 1u << b;
    for (int i = 0; i < d; ++i) m = (m ^ (m >> 1)) & 0xFFFu;
    return m;
}
__host__ __device__ constexpr unsigned selmask(int d, int b) {
    unsigned m = 1u << b;
    for (int i = 0; i < 16 - d; ++i) m = (m ^ ((m << 1) & 0xFFFu)) & 0xFFFu;
    return m;
}
__host__ __device__ constexpr int cpopc(unsigned v) {
    int c = 0; while (v) { c += (int)(v & 1u); v >>= 1; } return c;
}

template<int I, int N, class F>
__device__ __forceinline__ void sfor(F&& f) {
    if constexpr (I < N) {
        f(std::integral_constant<int, I>{});
        sfor<I + 1, N>(static_cast<F&&>(f));
    }
}

// ---- cross-lane primitives (R5/R7/R9-proven set ONLY) ----
template<int CTRL>
__device__ __forceinline__ float dppx(float v) {
    int iv = __float_as_int(v);
    return __int_as_float(__builtin_amdgcn_update_dpp(iv, iv, CTRL, 0xF, 0xF, false));
}
template<int M4>
__device__ __forceinline__ float lxor_low(float v) {
    static_assert(M4 >= 1 && M4 <= 15, "low mask");
    if constexpr      (M4 == 1)  return dppx<0xB1>(v);    // quad_perm xor1
    else if constexpr (M4 == 2)  return dppx<0x4E>(v);    // quad_perm xor2
    else if constexpr (M4 == 3)  return dppx<0x1B>(v);    // quad_perm xor3
    else if constexpr (M4 == 7)  return dppx<0x141>(v);   // row_half_mirror
    else if constexpr (M4 == 15) return dppx<0x140>(v);   // row_mirror
    else if constexpr ((M4 & 8) == 0)   // 4,5,6 = 7 ^ {3,2,1}
        return lxor_low<M4 ^ 7>(dppx<0x141>(v));
    else                                // 8..14 = 15 ^ {7..1}
        return lxor_low<M4 ^ 15>(dppx<0x140>(v));
}
template<int MASK>
__device__ __forceinline__ float lxor(float v) {
    static_assert(MASK > 0 && MASK < 64, "lane mask");
    if constexpr (MASK >= 32) {
        return __shfl_xor(v, MASK, 64);
    } else if constexpr (MASK >= 16) {
        // ds_swizzle BitMode: (xor<<10) | (or<<5) | and(0x1F)
        return __int_as_float(__builtin_amdgcn_ds_swizzle(__float_as_int(v),
                                                          (MASK << 10) | 0x1F));
    } else {
        return lxor_low<MASK>(v);
    }
}

// ---- pure-register gate (b<=1), tan form: 1 fma/elem ----
template<int D, int B>
__device__ __forceinline__ void gate_reg(float (&st)[NREG], int tid, float t) {
    constexpr unsigned V = axmask(D, B), M = selmask(D, B);
    static_assert((V >> 2) == 0 && V != 0, "reg gate");
    constexpr int VR = (int)V;
    constexpr unsigned MR = M & 3u, MT = M >> 2;
    const float tp = (__popc(MT & (unsigned)tid) & 1) ? t : -t;
    const float tn = -tp;
    sfor<0, NREG>([&](auto RC) {
        constexpr int r = RC.value, r2 = r ^ VR;
        if constexpr (r2 > r) {
            constexpr bool p0 = (cpopc(MR & (unsigned)r)  & 1) != 0;
            constexpr bool p1 = (cpopc(MR & (unsigned)r2) & 1) != 0;
            float a0 = st[r];
            st[r]  = fmaf(p0 ? tn : tp, st[r2], st[r]);
            st[r2] = fmaf(p1 ? tn : tp, a0,     st[r2]);
        }
    });
}

// ---- intra-wave lane-crossing gate (b=2..7), tan form ----
template<int D, int B>
__device__ __forceinline__ void gate_lane(float (&st)[NREG], int tid, float t) {
    constexpr unsigned V = axmask(D, B), M = selmask(D, B);
    constexpr int VT = (int)(V >> 2), VR = (int)(V & 3u);
    static_assert(VT > 0 && VT < 64, "intra-wave gate");
    static_assert((M & 3u) == 0, "no reg bits in selector for b>=2");
    const float tp = (__popc((M >> 2) & (unsigned)tid) & 1) ? t : -t;
    if constexpr (VR == 0) {
        sfor<0, NREG>([&](auto RC) {
            constexpr int r = RC.value;
            float p = lxor<VT>(st[r]);      // SIMD-lockstep: reads pre-update
            st[r] = fmaf(tp, p, st[r]);
        });
    } else {
        sfor<0, NREG>([&](auto RC) {
            constexpr int r = RC.value, r2 = r ^ VR;
            if constexpr (r2 > r) {
                float pa = lxor<VT>(st[r2]);
                float pb = lxor<VT>(st[r]);
                st[r]  = fmaf(tp, pa, st[r]);
                st[r2] = fmaf(tp, pb, st[r2]);
            }
        });
    }
}

// ---- fused thread-crossing pair (BH applied first, then BL) ----
// x'' = x + t1 x^V1 + t2 x^V2 + sigma t1 t2 x^(V1^V2),
// sigma = (-1)^parity(M1 & V2)  (general constexpr sign, no identity needed)
template<int D, int BH, int BL>
__device__ __forceinline__ void cross2(float (&st)[NREG], int tid,
                                       float t1, float t2,
                                       float* __restrict__ buf) {
    constexpr unsigned V1 = axmask(D, BH), V2 = axmask(D, BL);
    constexpr unsigned M1 = selmask(D, BH), M2 = selmask(D, BL);
    static_assert((V1 & 3u) == 0 && (V2 & 3u) == 0, "cross axes reg-free");
    static_assert((M1 & 3u) == 0 && (M2 & 3u) == 0, "cross masks reg-free");
    constexpr int T1 = (int)(V1 >> 2), T2 = (int)(V2 >> 2);
    static_assert(T1 > 0 && T2 > 0, "thread-crossing");
    constexpr int s12 = cpopc(M1 & V2) & 1;

    const float t1p = (__popc((M1 >> 2) & (unsigned)tid) & 1) ? t1 : -t1;
    const float t2p = (__popc((M2 >> 2) & (unsigned)tid) & 1) ? t2 : -t2;
    const float t12 = (s12 ? -1.f : 1.f) * t1p * t2p;

    *reinterpret_cast<float4*>(&buf[tid * 4]) =
        make_float4(st[0], st[1], st[2], st[3]);
    __syncthreads();
    const int p1 = (tid ^ T1) * 4, p2 = (tid ^ T2) * 4,
              p3 = (tid ^ (T1 ^ T2)) * 4;
    float4 A  = *reinterpret_cast<const float4*>(&buf[p1]);
    float4 Bv = *reinterpret_cast<const float4*>(&buf[p2]);
    float4 Cv = *reinterpret_cast<const float4*>(&buf[p3]);
    float t;
    t = fmaf(t1p, A.x, st[0]); t = fmaf(t2p, Bv.x, t); st[0] = fmaf(t12, Cv.x, t);
    t = fmaf(t1p, A.y, st[1]); t = fmaf(t2p, Bv.y, t); st[1] = fmaf(t12, Cv.y, t);
    t = fmaf(t1p, A.z, st[2]); t = fmaf(t2p, Bv.z, t); st[2] = fmaf(t12, Cv.z, t);
    t = fmaf(t1p, A.w, st[3]); t = fmaf(t2p, Bv.w, t); st[3] = fmaf(t12, Cv.w, t);
}

// ---- one depth: two cross exchanges, then lane gates, then reg gates ----
template<int D>
__device__ __forceinline__ void depth_apply(float (&st)[NREG], int tid,
                                            const float* __restrict__ tsh,
                                            float* __restrict__ ldsA,
                                            float* __restrict__ ldsB) {
    float4 ta = *reinterpret_cast<const float4*>(&tsh[D * 12 + 0]);
    float4 tb = *reinterpret_cast<const float4*>(&tsh[D * 12 + 4]);
    float4 tc = *reinterpret_cast<const float4*>(&tsh[D * 12 + 8]);
    float tq[12] = {ta.x, ta.y, ta.z, ta.w, tb.x, tb.y, tb.z, tb.w,
                    tc.x, tc.y, tc.z, tc.w};
    cross2<D, 11, 10>(st, tid, tq[0], tq[1], ldsA + (D & 1) * DIM);
    cross2<D,  9,  8>(st, tid, tq[2], tq[3], ldsB + (D & 1) * DIM);
    gate_lane<D, 7>(st, tid, tq[4]);
    gate_lane<D, 6>(st, tid, tq[5]);
    gate_lane<D, 5>(st, tid, tq[6]);
    gate_lane<D, 4>(st, tid, tq[7]);
    gate_lane<D, 3>(st, tid, tq[8]);
    gate_lane<D, 2>(st, tid, tq[9]);
    gate_reg<D, 1>(st, tid, tq[10]);
    gate_reg<D, 0>(st, tid, tq[11]);
}

__global__ __launch_bounds__(NT, 1)
void qnet_kernel(const float* __restrict__ x,       // [NBATCH, NQ]
                 const float* __restrict__ thetas,  // [DEPTH, NQ]
                 float* __restrict__ out)           // [NBATCH, 3]
{
    __shared__ __align__(16) float ldsA[2 * DIM];   // 32 KB pair-A buffers
    __shared__ __align__(16) float ldsB[2 * DIM];   // 32 KB pair-B buffers
    __shared__ __align__(16) float tsh[80];         // tan table (72 used)
    __shared__ __align__(16) float csh[80];         // cos table (72 used)
    __shared__ float red[16];                       // per-wave sums

    const int b   = blockIdx.x;
    const int tid = threadIdx.x;

    // ---- gate trig tables, once per block ----
    if (tid < 72) {
        float rev = thetas[tid] * 0.07957747154594767f;  // (th/2)/(2pi)
        float cc  = __builtin_amdgcn_cosf(rev);
        float ss  = __builtin_amdgcn_sinf(rev);
        csh[tid] = cc;
        tsh[tid] = ss * __builtin_amdgcn_rcpf(cc);
    }

    // ---- encoder: x*pi/2 rad = x/4 rev ----
    const float4* xv = reinterpret_cast<const float4*>(x + b * 12);
    float4 xa = xv[0], xb = xv[1], xc = xv[2];
    float xs[12] = {xa.x, xa.y, xa.z, xa.w, xb.x, xb.y, xb.z, xb.w,
                    xc.x, xc.y, xc.z, xc.w};
    float cq[12], sq[12];
    sfor<0, 12>([&](auto QC) {
        constexpr int q = QC.value;
        float rev = xs[q] * 0.25f;
        sq[q] = __builtin_amdgcn_sinf(rev);
        cq[q] = __builtin_amdgcn_cosf(rev);
    });

    // product state: j = (tid<<2)|r; j bit (2+i) = tid bit i <-> qubit 9-i;
    // j bit i (i<2) = reg bit i <-> qubit 11-i
    float la = 1.0f;
    sfor<0, 10>([&](auto IC) {
        constexpr int i = IC.value;
        la *= ((tid >> i) & 1) ? sq[9 - i] : cq[9 - i];
    });
    float st[NREG];
    st[0] = la;
    sfor<0, 2>([&](auto IC) {
        constexpr int i = IC.value;
        sfor<0, (1 << i)>([&](auto KC) {
            constexpr int k = KC.value;
            float base = st[k];
            st[k + (1 << i)] = base * sq[11 - i];
            st[k]            = base * cq[11 - i];
        });
    });

    __syncthreads();   // trig tables ready

    // ---- 6 depths ----
    sfor<0, 6>([&](auto DC) {
        depth_apply<DC.value>(st, tid, tsh, ldsA, ldsB);
    });

    // ---- global scale: sc = prod of all 72 cos ----
    float sc = 1.0f;
    sfor<0, 18>([&](auto IC) {
        constexpr int i = IC.value;
        float4 c4 = *reinterpret_cast<const float4*>(&csh[4 * i]);
        sc *= (c4.x * c4.y) * (c4.z * c4.w);
    });

    // ---- observer ----
    float tot = 0.0f;
    sfor<0, NREG>([&](auto RC) {
        constexpr int r = RC.value;
        tot = fmaf(st[r], st[r], tot);
    });
    tot *= sc * sc;   // undo tan normalization once

    // unsigned 64-lane butterfly (observer signs are wave-uniform here)
    float v = tot;
    v += lxor<1>(v);
    v += lxor<2>(v);
    v += lxor<4>(v);
    v += lxor<8>(v);
    v += lxor<16>(v);
    v += lxor<32>(v);
    const int w = tid >> 6;                 // wave index 0..15
    if ((tid & 63) == 0) red[w] = v;
    __syncthreads();
    // signs: q0 -> j bit 11 = w bit 3; q1 -> j bit 10 = w bit 2;
    //        q2 -> j bits 11^9 = w bits 3^1
    if (tid < 3) {
        float acc = 0.0f;
        #pragma unroll
        for (int ww = 0; ww < 16; ++ww) {
            int par = (tid == 0) ? ((ww >> 3) & 1)
                    : (tid == 1) ? ((ww >> 2) & 1)
                    :              (((ww >> 3) ^ (ww >> 1)) & 1);
            acc += par ? -red[ww] : red[ww];
        }
        out[b * 3 + tid] = acc;
    }
}

extern "C" void kernel_launch(void* const* d_in, const int* in_sizes, int n_in,
                              void* d_out, int out_size, void* d_ws, size_t ws_size,
                              hipStream_t stream) {
    (void)in_sizes; (void)n_in; (void)out_size; (void)d_ws; (void)ws_size;
    const float* x      = (const float*)d_in[0];   // [256,12] f32
    const float* thetas = (const float*)d_in[1];   // [6,12]   f32
    float* out          = (float*)d_out;           // [256,3]  f32

    qnet_kernel<<<dim3(NBATCH), dim3(NT), 0, stream>>>(x, thetas, out);
}

// Round 15
// 14.438 us; speedup vs baseline: 1.0561x; 1.0364x over previous
//
#include <hip/hip_runtime.h>
#include <math.h>
#include <type_traits>

#define NQ     12
#define DIM    4096
#define DEPTH  6
#define NBATCH 256
#define NT     512     // 8 waves per block -> 2 waves per SIMD (measured best)
#define NREG   8       // state elements per thread

// ---------------------------------------------------------------------------
// CHAMPION (R9, 14.38us) restored after structure-space exploration R10-R14.
//
// CNOT-ladder perm = Gray map g(j)=j^(j>>1), linear over GF(2)^12; all perms
// folded into gates: depth-d gate on logical bit b = butterfly on XOR-axis
// V = A^d e_b, sign selector M = row b of A^{-d} (A^16=I):
//   new[j] = x[j] + tau(j)*x[j^V],  tau(j) = parity(M&j) ? +t : -t, t=tan(th/2)
// (tan-normalized; global scale prod(cos) applied once in the observer).
// Storage j = (tid<<3)|r, tid 0..511, r 0..7.
//   b<=2   -> register butterfly (1 fma/elem)
//   b=3..8 -> intra-wave lane-xor: DPP(<16) / ds_swizzle(16..31) / shfl(>=32)
//   b=9    -> LDS pair exchange; b=10,11 -> fused cross2. 2 barriers/depth.
//
// Explored and rejected (measured):
//   cross3 1-barrier fuse      16.4us  (LDS op count > barrier count)
//   permlane16/32 lane gates   16.1us  (xor-combine overhead > DS savings)
//   DPP gate-pair fusion       15.2us  (3 lxor/elem for 2 gates > 2)
//   anti-packing LDS pad       14.6us  (no packing was occurring)
//   NT=1024 4 waves/SIMD       15.0us  (barrier convergence eats the gain)
//   NT=256  1 wave/SIMD        15.7us
// Floor: 72 serial gate stages + 12 barriers at 25% occupancy + sub-max DVFS
// clock for a ~14us replay kernel. Issued work ~1us; remainder is latency.
// ---------------------------------------------------------------------------

__host__ __device__ constexpr unsigned axmask(int d, int b) {
    unsigned m = 1u << b;
    for (int i = 0; i < d; ++i) m = (m ^ (m >> 1)) & 0xFFFu;
    return m;
}
__host__ __device__ constexpr unsigned selmask(int d, int b) {
    unsigned m = 1u << b;
    for (int i = 0; i < 16 - d; ++i) m = (m ^ ((m << 1) & 0xFFFu)) & 0xFFFu;
    return m;
}
__host__ __device__ constexpr int cpopc(unsigned v) {
    int c = 0; while (v) { c += (int)(v & 1u); v >>= 1; } return c;
}

template<int I, int N, class F>
__device__ __forceinline__ void sfor(F&& f) {
    if constexpr (I < N) {
        f(std::integral_constant<int, I>{});
        sfor<I + 1, N>(static_cast<F&&>(f));
    }
}

// ---- cross-lane primitives (proven set) ----
template<int CTRL>
__device__ __forceinline__ float dppx(float v) {
    int iv = __float_as_int(v);
    return __int_as_float(__builtin_amdgcn_update_dpp(iv, iv, CTRL, 0xF, 0xF, false));
}
template<int M4>
__device__ __forceinline__ float lxor_low(float v) {
    static_assert(M4 >= 1 && M4 <= 15, "low mask");
    if constexpr      (M4 == 1)  return dppx<0xB1>(v);    // quad_perm xor1
    else if constexpr (M4 == 2)  return dppx<0x4E>(v);    // quad_perm xor2
    else if constexpr (M4 == 3)  return dppx<0x1B>(v);    // quad_perm xor3
    else if constexpr (M4 == 7)  return dppx<0x141>(v);   // row_half_mirror
    else if constexpr (M4 == 15) return dppx<0x140>(v);   // row_mirror
    else if constexpr ((M4 & 8) == 0)   // 4,5,6 = 7 ^ {3,2,1}
        return lxor_low<M4 ^ 7>(dppx<0x141>(v));
    else                                // 8..14 = 15 ^ {7..1}
        return lxor_low<M4 ^ 15>(dppx<0x140>(v));
}
template<int MASK>
__device__ __forceinline__ float lxor(float v) {
    static_assert(MASK > 0 && MASK < 64, "lane mask");
    if constexpr (MASK >= 32) {
        return __shfl_xor(v, MASK, 64);
    } else if constexpr (MASK >= 16) {
        // ds_swizzle BitMode: (xor<<10) | (or<<5) | and(0x1F)
        return __int_as_float(__builtin_amdgcn_ds_swizzle(__float_as_int(v),
                                                          (MASK << 10) | 0x1F));
    } else {
        return lxor_low<MASK>(v);
    }
}

// swizzled LDS word address: thread t, chunk k in 0..1, 8 floats/thread
__device__ __forceinline__ int lad(int t, int k) {
    return t * 8 + 4 * (k ^ ((t >> 2) & 1));
}

// ---- pure-register gate (b<=2), tan form: 1 fma/elem ----
template<int D, int B>
__device__ __forceinline__ void gate_reg(float (&st)[NREG], int tid, float t) {
    constexpr unsigned V = axmask(D, B), M = selmask(D, B);
    static_assert((V >> 3) == 0 && V != 0, "reg gate");
    constexpr int VR = (int)V;
    constexpr unsigned MR = M & 7u, MT = M >> 3;
    const float tp = (__popc(MT & (unsigned)tid) & 1) ? t : -t;
    const float tn = -tp;
    sfor<0, NREG>([&](auto RC) {
        constexpr int r = RC.value, r2 = r ^ VR;
        if constexpr (r2 > r) {
            constexpr bool p0 = (cpopc(MR & (unsigned)r)  & 1) != 0;
            constexpr bool p1 = (cpopc(MR & (unsigned)r2) & 1) != 0;
            float a0 = st[r];
            st[r]  = fmaf(p0 ? tn : tp, st[r2], st[r]);
            st[r2] = fmaf(p1 ? tn : tp, a0,     st[r2]);
        }
    });
}

// ---- intra-wave lane-crossing gate (b=3..8), tan form ----
template<int D, int B>
__device__ __forceinline__ void gate_lane(float (&st)[NREG], int tid, float t) {
    constexpr unsigned V = axmask(D, B), M = selmask(D, B);
    constexpr int VT = (int)(V >> 3), VR = (int)(V & 7u);
    static_assert(VT > 0 && VT < 64, "intra-wave gate");
    static_assert((M & 7u) == 0, "no reg bits in selector for b>=3");
    const float tp = (__popc((M >> 3) & (unsigned)tid) & 1) ? t : -t;
    if constexpr (VR == 0) {
        sfor<0, NREG>([&](auto RC) {
            constexpr int r = RC.value;
            float p = lxor<VT>(st[r]);      // SIMD-lockstep: reads pre-update
            st[r] = fmaf(tp, p, st[r]);
        });
    } else {
        sfor<0, NREG>([&](auto RC) {
            constexpr int r = RC.value, r2 = r ^ VR;
            if constexpr (r2 > r) {
                float pa = lxor<VT>(st[r2]);
                float pb = lxor<VT>(st[r]);
                st[r]  = fmaf(tp, pa, st[r]);
                st[r2] = fmaf(tp, pb, st[r2]);
            }
        });
    }
}

// ---- b=9 gate: LDS pair exchange (crosses wave bits) ----
template<int D>
__device__ __forceinline__ void gate9x(float (&st)[NREG], int tid, float t,
                                       float* __restrict__ lds9) {
    constexpr unsigned V = axmask(D, 9), M = selmask(D, 9);
    static_assert((V & 7u) == 0 && (M & 7u) == 0, "b9 reg-pure-free");
    constexpr int T = (int)(V >> 3);
    static_assert(T >= 64 && T < 512, "b9 crosses waves");
    const float tp = (__popc((M >> 3) & (unsigned)tid) & 1) ? t : -t;
    float* buf = lds9 + (D & 1) * DIM;
    sfor<0, 2>([&](auto KC) {
        constexpr int k = KC.value;
        *reinterpret_cast<float4*>(&buf[lad(tid, k)]) =
            make_float4(st[4*k], st[4*k+1], st[4*k+2], st[4*k+3]);
    });
    __syncthreads();
    const int p = tid ^ T;
    sfor<0, 2>([&](auto KC) {
        constexpr int k = KC.value;
        float4 pv = *reinterpret_cast<const float4*>(&buf[lad(p, k)]);
        st[4*k+0] = fmaf(tp, pv.x, st[4*k+0]);
        st[4*k+1] = fmaf(tp, pv.y, st[4*k+1]);
        st[4*k+2] = fmaf(tp, pv.z, st[4*k+2]);
        st[4*k+3] = fmaf(tp, pv.w, st[4*k+3]);
    });
}

// ---- fused cross pair (b=11,10), tan form: 3 fma/elem ----
template<int D>
__device__ __forceinline__ void cross2(float (&st)[NREG], int tid,
                                       float t1, float t2,
                                       float* __restrict__ lds2) {
    constexpr unsigned V1 = axmask(D, 11), V2 = axmask(D, 10);
    constexpr unsigned M1 = selmask(D, 11), M2 = selmask(D, 10);
    static_assert((V1 & 7u) == 0 && (V2 & 7u) == 0, "cross axes reg-free");
    static_assert((M1 & 7u) == 0 && (M2 & 7u) == 0, "cross masks reg-free");
    constexpr int T1 = (int)(V1 >> 3), T2 = (int)(V2 >> 3);
    static_assert((cpopc(M1 & V2) & 1) == 0, "kC sign identity");

    const float t1p = (__popc((M1 >> 3) & (unsigned)tid) & 1) ? t1 : -t1;
    const float t2p = (__popc((M2 >> 3) & (unsigned)tid) & 1) ? t2 : -t2;
    const float t12 = t1p * t2p;

    float* buf = lds2 + (D & 1) * DIM;
    sfor<0, 2>([&](auto KC) {
        constexpr int k = KC.value;
        *reinterpret_cast<float4*>(&buf[lad(tid, k)]) =
            make_float4(st[4*k], st[4*k+1], st[4*k+2], st[4*k+3]);
    });
    __syncthreads();
    const int p1 = tid ^ T1, p2 = tid ^ T2, p3 = tid ^ (T1 ^ T2);
    sfor<0, 2>([&](auto KC) {
        constexpr int k = KC.value;
        float4 A  = *reinterpret_cast<const float4*>(&buf[lad(p1, k)]);
        float4 Bv = *reinterpret_cast<const float4*>(&buf[lad(p2, k)]);
        float4 Cv = *reinterpret_cast<const float4*>(&buf[lad(p3, k)]);
        float t;
        t = fmaf(t1p, A.x, st[4*k+0]); t = fmaf(t2p, Bv.x, t); st[4*k+0] = fmaf(t12, Cv.x, t);
        t = fmaf(t1p, A.y, st[4*k+1]); t = fmaf(t2p, Bv.y, t); st[4*k+1] = fmaf(t12, Cv.y, t);
        t = fmaf(t1p, A.z, st[4*k+2]); t = fmaf(t2p, Bv.z, t); st[4*k+2] = fmaf(t12, Cv.z, t);
        t = fmaf(t1p, A.w, st[4*k+3]); t = fmaf(t2p, Bv.w, t); st[4*k+3] = fmaf(t12, Cv.w, t);
    });
}

// ---- one depth: taus from LDS table ----
template<int D>
__device__ __forceinline__ void depth_apply(float (&st)[NREG], int tid,
                                            const float* __restrict__ tsh,
                                            float* __restrict__ lds2,
                                            float* __restrict__ lds9) {
    float4 ta = *reinterpret_cast<const float4*>(&tsh[D * 12 + 0]);
    float4 tb = *reinterpret_cast<const float4*>(&tsh[D * 12 + 4]);
    float4 tc = *reinterpret_cast<const float4*>(&tsh[D * 12 + 8]);
    float tq[12] = {ta.x, ta.y, ta.z, ta.w, tb.x, tb.y, tb.z, tb.w,
                    tc.x, tc.y, tc.z, tc.w};
    cross2<D>(st, tid, tq[0], tq[1], lds2);    // b = 11, 10
    gate9x<D>(st, tid, tq[2], lds9);           // b = 9
    sfor<3, 12>([&](auto QC) {                 // b = 8..0
        constexpr int Q = QC.value, B = 11 - Q;
        if constexpr (B >= 3) gate_lane<D, B>(st, tid, tq[Q]);
        else                  gate_reg <D, B>(st, tid, tq[Q]);
    });
}

__global__ __launch_bounds__(NT, 2)
void qnet_kernel(const float* __restrict__ x,       // [NBATCH, NQ]
                 const float* __restrict__ thetas,  // [DEPTH, NQ]
                 float* __restrict__ out)           // [NBATCH, 3]
{
    __shared__ __align__(16) float lds2[2 * DIM];   // 32 KB cross2 buffers
    __shared__ __align__(16) float lds9[2 * DIM];   // 32 KB gate9 buffers
    __shared__ __align__(16) float tsh[80];         // tan table (72 used)
    __shared__ __align__(16) float csh[80];         // cos table (72 used)
    __shared__ float red[8];                        // per-wave sums

    const int b   = blockIdx.x;
    const int tid = threadIdx.x;

    // ---- gate trig tables, once per block ----
    if (tid < 72) {
        float rev = thetas[tid] * 0.07957747154594767f;  // (th/2)/(2pi)
        float cc  = __builtin_amdgcn_cosf(rev);
        float ss  = __builtin_amdgcn_sinf(rev);
        csh[tid] = cc;
        tsh[tid] = ss * __builtin_amdgcn_rcpf(cc);
    }

    // ---- encoder: x*pi/2 rad = x/4 rev ----
    const float4* xv = reinterpret_cast<const float4*>(x + b * 12);
    float4 xa = xv[0], xb = xv[1], xc = xv[2];
    float xs[12] = {xa.x, xa.y, xa.z, xa.w, xb.x, xb.y, xb.z, xb.w,
                    xc.x, xc.y, xc.z, xc.w};
    float cq[12], sq[12];
    sfor<0, 12>([&](auto QC) {
        constexpr int q = QC.value;
        float rev = xs[q] * 0.25f;
        sq[q] = __builtin_amdgcn_sinf(rev);
        cq[q] = __builtin_amdgcn_cosf(rev);
    });

    // product state: j = (tid<<3)|r; j bit (3+i) = tid bit i <-> qubit 8-i;
    // j bit i (i<3) = reg bit i <-> qubit 11-i
    float la = 1.0f;
    sfor<0, 9>([&](auto IC) {
        constexpr int i = IC.value;
        la *= ((tid >> i) & 1) ? sq[8 - i] : cq[8 - i];
    });
    float st[NREG];
    st[0] = la;
    sfor<0, 3>([&](auto IC) {
        constexpr int i = IC.value;
        sfor<0, (1 << i)>([&](auto KC) {
            constexpr int k = KC.value;
            float base = st[k];
            st[k + (1 << i)] = base * sq[11 - i];
            st[k]            = base * cq[11 - i];
        });
    });

    __syncthreads();   // trig tables ready

    // ---- 6 depths ----
    sfor<0, 6>([&](auto DC) {
        depth_apply<DC.value>(st, tid, tsh, lds2, lds9);
    });

    // ---- global scale: sc = prod of all 72 cos ----
    float sc = 1.0f;
    sfor<0, 18>([&](auto IC) {
        constexpr int i = IC.value;
        float4 c4 = *reinterpret_cast<const float4*>(&csh[4 * i]);
        sc *= (c4.x * c4.y) * (c4.z * c4.w);
    });

    // ---- observer ----
    float tot = 0.0f;
    sfor<0, NREG>([&](auto RC) {
        constexpr int r = RC.value;
        tot = fmaf(st[r], st[r], tot);
    });
    tot *= sc * sc;   // undo tan normalization once

    // full 64-lane butterfly sum
    float v = tot;
    v += lxor<1>(v);
    v += lxor<2>(v);
    v += lxor<4>(v);
    v += lxor<8>(v);
    v += lxor<16>(v);
    v += lxor<32>(v);
    const int w = tid >> 6;
    if ((tid & 63) == 0) red[w] = v;
    __syncthreads();
    // signs on stored index: q0 -> j bit 11 = w bit 2; q1 -> j bit 10 = w bit 1;
    // q2 -> j bits 11^9 = w bits 2^0
    if (tid < 3) {
        float acc = 0.0f;
        #pragma unroll
        for (int ww = 0; ww < 8; ++ww) {
            int par = (tid == 0) ? ((ww >> 2) & 1)
                    : (tid == 1) ? ((ww >> 1) & 1)
                    :              (((ww >> 2) ^ ww) & 1);
            acc += par ? -red[ww] : red[ww];
        }
        out[b * 3 + tid] = acc;
    }
}

extern "C" void kernel_launch(void* const* d_in, const int* in_sizes, int n_in,
                              void* d_out, int out_size, void* d_ws, size_t ws_size,
                              hipStream_t stream) {
    (void)in_sizes; (void)n_in; (void)out_size; (void)d_ws; (void)ws_size;
    const float* x      = (const float*)d_in[0];   // [256,12] f32
    const float* thetas = (const float*)d_in[1];   // [6,12]   f32
    float* out          = (float*)d_out;           // [256,3]  f32

    qnet_kernel<<<dim3(NBATCH), dim3(NT), 0, stream>>>(x, thetas, out);
}